// Round 1
// baseline (274.343 us; speedup 1.0000x reference)
//
#include <hip/hip_runtime.h>
#include <cstdint>

// ---------------------------------------------------------------------------
// Causal self-attention block: qkv GEMM -> flash attention (32x32 MFMA,
// direct-from-L2 K/V reads, zero LDS, zero barriers) -> proj GEMM.
// bf16 MFMA, fp32 accumulate. B=4 S=2048 E=768 H=12 D=64.
// ---------------------------------------------------------------------------

typedef __bf16 bf16x8 __attribute__((ext_vector_type(8)));
typedef __bf16 bf16x4 __attribute__((ext_vector_type(4)));
typedef float  f32x4  __attribute__((ext_vector_type(4)));
typedef float  f32x16 __attribute__((ext_vector_type(16)));

#define MFMA16(a, b, c) __builtin_amdgcn_mfma_f32_16x16x32_bf16(a, b, c, 0, 0, 0)
#define MFMA32(a, b, c) __builtin_amdgcn_mfma_f32_32x32x16_bf16(a, b, c, 0, 0, 0)

static constexpr int Bb = 4, Ss = 2048, Ee = 768, Hh = 12, Dd = 64;
// softmax scale 1/8 folded with log2(e) so we can use raw v_exp_f32 (2^x)
#define QSCALE 0.18033688011112042f

__device__ __forceinline__ void gl2lds16(const void* g, void* l) {
  __builtin_amdgcn_global_load_lds(
      (const __attribute__((address_space(1))) void*)g,
      (__attribute__((address_space(3))) void*)l, 16, 0, 0);
}

__device__ __forceinline__ float fexp2(float x) {
#if __has_builtin(__builtin_amdgcn_exp2f)
  return __builtin_amdgcn_exp2f(x);
#else
  return exp2f(x);
#endif
}

// swap bits 2<->3: the shared MFMA k-slot permutation baked into Q/K/V layouts
__device__ __forceinline__ int swap23(int x) {
  return (x & ~12) | ((x & 4) << 1) | ((x & 8) >> 1);
}

// ---------------------------------------------------------------------------
// prep kernels
// ---------------------------------------------------------------------------
__global__ void cast_f32_bf16(const float* __restrict__ x,
                              __bf16* __restrict__ y, int n) {
  int i = (blockIdx.x * blockDim.x + threadIdx.x) * 4;
  if (i < n) {
    float4 v = *(const float4*)(x + i);
    bf16x4 o = {(__bf16)v.x, (__bf16)v.y, (__bf16)v.z, (__bf16)v.w};
    *(bf16x4*)(y + i) = o;
  }
}

__global__ void transpose_cast(const float* __restrict__ W,
                               __bf16* __restrict__ Wt, int K, int N) {
  __shared__ float t[64][65];
  const int k0 = blockIdx.y * 64, n0 = blockIdx.x * 64;
#pragma unroll
  for (int i = 0; i < 16; ++i) {
    int lin = i * 256 + threadIdx.x;
    int r = lin >> 6, c = lin & 63;
    t[r][c] = W[(size_t)(k0 + r) * N + n0 + c];
  }
  __syncthreads();
#pragma unroll
  for (int i = 0; i < 16; ++i) {
    int lin = i * 256 + threadIdx.x;
    int r = lin >> 6, c = lin & 63;
    Wt[(size_t)(n0 + r) * K + k0 + c] = (__bf16)t[c][r];
  }
}

// ---------------------------------------------------------------------------
// m97-style GEMM: C[M,N] = A[M,K] @ Bt[N,K]^T, 128x128 tile, BK=32.
// MODE 0: qkv epilogue -- bias; Q scaled by log2(e)/8; Q/K d-index and V^T
//         s-index permuted via swap23 (flash fragment layout).
// MODE 1: proj epilogue (bias, fp32 out)
// ---------------------------------------------------------------------------
template <int MODE>
__global__ __launch_bounds__(256) void gemm_bt(
    const __bf16* __restrict__ A, const __bf16* __restrict__ Bt,
    const float* __restrict__ bias, __bf16* __restrict__ Qb,
    __bf16* __restrict__ Kb, __bf16* __restrict__ VTb,
    float* __restrict__ out, int K, int N) {
  __shared__ __align__(16) __bf16 As[128 * 32];
  __shared__ __align__(16) __bf16 Bs[128 * 32];
  const int tid = threadIdx.x;
  const int wave = tid >> 6, lane = tid & 63;
  const int quad = lane >> 4, c16 = lane & 15;
  const int m0 = blockIdx.y * 128, n0 = blockIdx.x * 128;
  const int wm = (wave >> 1) * 64, wn = (wave & 1) * 64;

  f32x4 acc[4][4] = {};

  for (int k0 = 0; k0 < K; k0 += 32) {
    __syncthreads();
#pragma unroll
    for (int i = 0; i < 2; ++i) {
      const int cb = (i * 4 + wave) * 64;
      const int c = cb + lane;
      const int row = c >> 2, kk = (c & 3) * 8;
      gl2lds16(&A[(size_t)(m0 + row) * K + k0 + kk], &As[cb * 8]);
      gl2lds16(&Bt[(size_t)(n0 + row) * K + k0 + kk], &Bs[cb * 8]);
    }
    __syncthreads();
    bf16x8 af[4], bf[4];
#pragma unroll
    for (int mi = 0; mi < 4; ++mi)
      af[mi] = *(const bf16x8*)&As[(wm + mi * 16 + c16) * 32 + quad * 8];
#pragma unroll
    for (int ni = 0; ni < 4; ++ni)
      bf[ni] = *(const bf16x8*)&Bs[(wn + ni * 16 + c16) * 32 + quad * 8];
#pragma unroll
    for (int mi = 0; mi < 4; ++mi)
#pragma unroll
      for (int ni = 0; ni < 4; ++ni)
        acc[mi][ni] = MFMA16(af[mi], bf[ni], acc[mi][ni]);
  }

#pragma unroll
  for (int mi = 0; mi < 4; ++mi) {
#pragma unroll
    for (int ni = 0; ni < 4; ++ni) {
      const int gcol = n0 + wn + ni * 16 + c16;
      const float bv = bias[gcol];
      const int growb = m0 + wm + mi * 16 + quad * 4;
      if (MODE == 0) {
        const int which = gcol / Ee;
        const int e = gcol - which * Ee;
        const int hh = e >> 6, dd = e & 63;
        const int bb = growb >> 11, ss = growb & 2047;
        const size_t bh = (size_t)(bb * Hh + hh);
        if (which == 2) {  // V^T with permuted s: 4 consecutive ss stay packed
          const int ssp = swap23(ss);
          bf16x4 o;
#pragma unroll
          for (int r = 0; r < 4; ++r) o[r] = (__bf16)(acc[mi][ni][r] + bv);
          *(bf16x4*)&VTb[(bh * Dd + dd) * Ss + ssp] = o;
        } else if (which == 0) {  // Q: permuted d, prescaled
          const int ddp = swap23(dd);
#pragma unroll
          for (int r = 0; r < 4; ++r)
            Qb[(bh * Ss + ss + r) * Dd + ddp] =
                (__bf16)((acc[mi][ni][r] + bv) * QSCALE);
        } else {  // K: permuted d
          const int ddp = swap23(dd);
#pragma unroll
          for (int r = 0; r < 4; ++r)
            Kb[(bh * Ss + ss + r) * Dd + ddp] = (__bf16)(acc[mi][ni][r] + bv);
        }
      } else {
#pragma unroll
        for (int r = 0; r < 4; ++r)
          out[(size_t)(growb + r) * N + gcol] = acc[mi][ni][r] + bv;
      }
    }
  }
}

// ---------------------------------------------------------------------------
// flash attention v5: 32x32x16 MFMA; K/V fragments read DIRECTLY from global
// (L2-resident: XCD swizzle keeps 6 (b,h) -> 3MB of K/V per XCD L2; L1 absorbs
// the 8x chunk re-reads within a 16KB tile working set). Zero LDS, zero
// barriers -- every wave runs its own strip of 32 queries independently and
// loops only to its own diagonal (no staging-helper iterations). Strip->wave
// assignment rotates with bidx so same-SIMD waves get mixed strip lengths.
// Q/K/V global layouts carry the swap23 k-slot permutation (from gemm1), so
// all fragment reads are contiguous b128.
// ---------------------------------------------------------------------------
__global__ __launch_bounds__(256, 3) void flash_attn(
    const __bf16* __restrict__ Qb, const __bf16* __restrict__ Kb,
    const __bf16* __restrict__ VTb, const int* __restrict__ amask,
    __bf16* __restrict__ Yb) {
  const int bid = blockIdx.x;
  const int xcd = bid & 7, j = bid >> 3;
  const int bh = xcd * 6 + (j >> 4);  // 6 (b,h) per XCD for L2 locality
  const int bidx = j & 15;
  const int b = bh / Hh, h = bh - b * Hh;
  const int tid = threadIdx.x, w = tid >> 6, lane = tid & 63;
  const int hl = lane >> 5, l31 = lane & 31;

  // balanced strips {bidx, 31-bidx, 32+bidx, 63-bidx}; rotate role by bidx so
  // a given wave-slot (SIMD) sees a mix of strip lengths across blocks
  const int role = (w + bidx) & 3;
  const int s = ((role & 2) << 4) + ((role & 1) ? 31 - bidx : bidx);
  const int qs = s * 32;
  const int qg = qs + l31;   // this lane's query
  const int ktmax = s >> 1;  // last key-tile overlapping this wave's diagonal

  const __bf16* Qp = Qb + (size_t)bh * Ss * Dd;
  const __bf16* Kp = Kb + (size_t)bh * Ss * Dd;
  const __bf16* Vp = VTb + (size_t)bh * Dd * Ss;
  const int* mp = amask + b * Ss;

  // Q fragments: contiguous b128 thanks to permuted global layout
  bf16x8 qf[4];
#pragma unroll
  for (int wd = 0; wd < 4; ++wd)
    qf[wd] = *(const bf16x8*)&Qp[(size_t)qg * Dd + wd * 16 + hl * 8];

  f32x16 yacc[2] = {};  // Y^T[d = 32dt + (r&3)+8(r>>2)+4hl][q = l31]
  float m_i = -30000.f, l_i = 0.f;

  for (int kt = 0; kt <= ktmax; ++kt) {
    const int k0 = kt * 64;

    // attention-mask ballot for this tile (L2-hot; all-ones fast path below)
    const uint64_t mball = __ballot(mp[k0 + lane] != 0);

    // S^T = K @ Q^T over two 32-key groups (C rows = keys, cols = queries)
    f32x16 sg[2];
#pragma unroll
    for (int g = 0; g < 2; ++g) {
      f32x16 acc = {};
#pragma unroll
      for (int wd = 0; wd < 4; ++wd) {
        const bf16x8 kf = *(const bf16x8*)&Kp[(size_t)(k0 + g * 32 + l31) * Dd +
                                              wd * 16 + hl * 8];
        acc = MFMA32(kf, qf[wd], acc);
      }
      sg[g] = acc;
    }

    // causal mask: only tiles overlapping this wave's diagonal
    if (k0 + 63 > qs) {
#pragma unroll
      for (int g = 0; g < 2; ++g)
#pragma unroll
        for (int r = 0; r < 16; ++r) {
          const int key = k0 + g * 32 + (r & 3) + 8 * (r >> 2) + 4 * hl;
          sg[g][r] = (key <= qg) ? sg[g][r] : -30000.f;
        }
    }
    // attention mask: wave-uniform skip when tile fully valid
    if (mball != ~0ull) {
#pragma unroll
      for (int g = 0; g < 2; ++g)
#pragma unroll
        for (int r = 0; r < 16; ++r) {
          const int kr = g * 32 + (r & 3) + 8 * (r >> 2) + 4 * hl;
          sg[g][r] = ((mball >> kr) & 1) ? sg[g][r] : -30000.f;
        }
    }

    // online softmax in log2 domain; row = lane's q; tree-shaped reductions
    // (depth 5 instead of a 31-deep dependent fmax chain)
    float tm[16];
#pragma unroll
    for (int r = 0; r < 16; ++r) tm[r] = fmaxf(sg[0][r], sg[1][r]);
#pragma unroll
    for (int off = 8; off >= 1; off >>= 1)
#pragma unroll
      for (int r = 0; r < 8; ++r)
        if (r < off) tm[r] = fmaxf(tm[r], tm[r + off]);
    const float mx = fmaxf(tm[0], __shfl_xor(tm[0], 32));

    // defer-max (T13): if no lane's max grew more than 2^11.5 over m_i,
    // keep m_i and skip the O/l rescale entirely
    const bool grow = !__all(mx <= m_i + 11.5f);
    const float mnew = grow ? fmaxf(m_i, mx) : m_i;

    float ts[16];
#pragma unroll
    for (int r = 0; r < 16; ++r) {
      const float e0 = fexp2(sg[0][r] - mnew);
      const float e1 = fexp2(sg[1][r] - mnew);
      sg[0][r] = e0;
      sg[1][r] = e1;
      ts[r] = e0 + e1;
    }
#pragma unroll
    for (int off = 8; off >= 1; off >>= 1)
#pragma unroll
      for (int r = 0; r < 8; ++r)
        if (r < off) ts[r] += ts[r + off];
    float rs = ts[0] + __shfl_xor(ts[0], 32);

    if (grow) {
      const float alpha = fexp2(m_i - mnew);
      l_i *= alpha;
      m_i = mnew;
#pragma unroll
      for (int dt = 0; dt < 2; ++dt)
#pragma unroll
        for (int r = 0; r < 16; ++r) yacc[dt][r] *= alpha;
    }
    l_i += rs;

    // P^T B-fragments = S^T C-register groups (shared k-slot permutation)
    bf16x8 pf[4];
#pragma unroll
    for (int W = 0; W < 4; ++W) {
      bf16x8 f;
#pragma unroll
      for (int jj = 0; jj < 8; ++jj)
        f[jj] = (__bf16)sg[W >> 1][8 * (W & 1) + jj];
      pf[W] = f;
    }

    // Y^T += V^T @ P^T  (V^T fragments straight from global / L2)
#pragma unroll
    for (int dt = 0; dt < 2; ++dt)
#pragma unroll
      for (int W = 0; W < 4; ++W) {
        const bf16x8 vf = *(const bf16x8*)&Vp[(size_t)(dt * 32 + l31) * Ss +
                                              k0 + W * 16 + hl * 8];
        yacc[dt] = MFMA32(vf, pf[W], yacc[dt]);
      }
  }

  // normalize; write Y [B,S,E] bf16 (unpermuted -- feeds gemm2)
  const float inv = 1.f / l_i;
  __bf16* yrow = Yb + (size_t)(b * Ss + qg) * Ee + h * Dd;
#pragma unroll
  for (int dt = 0; dt < 2; ++dt)
#pragma unroll
    for (int sreg = 0; sreg < 4; ++sreg) {
      bf16x4 o;
#pragma unroll
      for (int r = 0; r < 4; ++r)
        o[r] = (__bf16)(yacc[dt][sreg * 4 + r] * inv);
      *(bf16x4*)&yrow[dt * 32 + sreg * 8 + hl * 4] = o;
    }
}

// ---------------------------------------------------------------------------
// launch
// ---------------------------------------------------------------------------
extern "C" void kernel_launch(void* const* d_in, const int* in_sizes, int n_in,
                              void* d_out, int out_size, void* d_ws,
                              size_t ws_size, hipStream_t stream) {
  const float* x      = (const float*)d_in[0];
  const float* W_attn = (const float*)d_in[1];
  const float* b_attn = (const float*)d_in[2];
  const float* W_proj = (const float*)d_in[3];
  const float* b_proj = (const float*)d_in[4];
  const int* att_mask = (const int*)d_in[5];
  float* out = (float*)d_out;

  char* ws = (char*)d_ws;
  __bf16* xb  = (__bf16*)(ws);              // 12,582,912  x as bf16 / later Y
  __bf16* Wat = (__bf16*)(ws + 12582912);   //  3,538,944  W_attn^T bf16
  __bf16* Wpt = (__bf16*)(ws + 16121856);   //  1,179,648  W_proj^T bf16
  __bf16* Qb  = (__bf16*)(ws + 17301504);   // Q [B,H,S,D] perm, x log2e/8
  __bf16* Kb  = (__bf16*)(ws + 29884416);   // K [B,H,S,D] perm
  __bf16* VTb = (__bf16*)(ws + 42467328);   // V^T [B,H,D,S] perm
  __bf16* Yb  = xb;

  cast_f32_bf16<<<6144, 256, 0, stream>>>(x, xb, Bb * Ss * Ee);
  transpose_cast<<<dim3(36, 12), 256, 0, stream>>>(W_attn, Wat, Ee, 3 * Ee);
  transpose_cast<<<dim3(12, 12), 256, 0, stream>>>(W_proj, Wpt, Ee, Ee);

  gemm_bt<0><<<dim3(18, 64), 256, 0, stream>>>(xb, Wat, b_attn, Qb, Kb, VTb,
                                               nullptr, Ee, 3 * Ee);
  flash_attn<<<768, 256, 0, stream>>>(Qb, Kb, VTb, att_mask, Yb);
  gemm_bt<1><<<dim3(6, 64), 256, 0, stream>>>(Yb, Wpt, b_proj, nullptr,
                                              nullptr, nullptr, out, Ee, Ee);
}

// Round 2
// 231.025 us; speedup vs baseline: 1.1875x; 1.1875x over previous
//
#include <hip/hip_runtime.h>
#include <cstdint>

// ---------------------------------------------------------------------------
// Causal self-attention block: qkv GEMM -> flash attention (32x32 MFMA,
// async 3-buffer staging) -> proj GEMM. bf16 MFMA, fp32 accumulate.
// B=4 S=2048 E=768 H=12 D=64.
// ---------------------------------------------------------------------------

typedef __bf16 bf16x8 __attribute__((ext_vector_type(8)));
typedef __bf16 bf16x4 __attribute__((ext_vector_type(4)));
typedef float  f32x4  __attribute__((ext_vector_type(4)));
typedef float  f32x16 __attribute__((ext_vector_type(16)));

#define MFMA16(a, b, c) __builtin_amdgcn_mfma_f32_16x16x32_bf16(a, b, c, 0, 0, 0)
#define MFMA32(a, b, c) __builtin_amdgcn_mfma_f32_32x32x16_bf16(a, b, c, 0, 0, 0)

static constexpr int Bb = 4, Ss = 2048, Ee = 768, Hh = 12, Dd = 64;
// softmax scale 1/8 folded with log2(e) so we can use raw v_exp_f32 (2^x)
#define QSCALE 0.18033688011112042f

__device__ __forceinline__ void gl2lds16(const void* g, void* l) {
  __builtin_amdgcn_global_load_lds(
      (const __attribute__((address_space(1))) void*)g,
      (__attribute__((address_space(3))) void*)l, 16, 0, 0);
}

__device__ __forceinline__ float fexp2(float x) {
#if __has_builtin(__builtin_amdgcn_exp2f)
  return __builtin_amdgcn_exp2f(x);
#else
  return exp2f(x);
#endif
}

// swap bits 2<->3: the shared MFMA k-slot permutation baked into Q/K/V layouts
__device__ __forceinline__ int swap23(int x) {
  return (x & ~12) | ((x & 4) << 1) | ((x & 8) >> 1);
}

// ---------------------------------------------------------------------------
// prep kernels
// ---------------------------------------------------------------------------
__global__ void cast_f32_bf16(const float* __restrict__ x,
                              __bf16* __restrict__ y, int n) {
  int i = (blockIdx.x * blockDim.x + threadIdx.x) * 4;
  if (i < n) {
    float4 v = *(const float4*)(x + i);
    bf16x4 o = {(__bf16)v.x, (__bf16)v.y, (__bf16)v.z, (__bf16)v.w};
    *(bf16x4*)(y + i) = o;
  }
}

__global__ void transpose_cast(const float* __restrict__ W,
                               __bf16* __restrict__ Wt, int K, int N) {
  __shared__ float t[64][65];
  const int k0 = blockIdx.y * 64, n0 = blockIdx.x * 64;
#pragma unroll
  for (int i = 0; i < 16; ++i) {
    int lin = i * 256 + threadIdx.x;
    int r = lin >> 6, c = lin & 63;
    t[r][c] = W[(size_t)(k0 + r) * N + n0 + c];
  }
  __syncthreads();
#pragma unroll
  for (int i = 0; i < 16; ++i) {
    int lin = i * 256 + threadIdx.x;
    int r = lin >> 6, c = lin & 63;
    Wt[(size_t)(n0 + r) * K + k0 + c] = (__bf16)t[c][r];
  }
}

// ---------------------------------------------------------------------------
// m97-style GEMM: C[M,N] = A[M,K] @ Bt[N,K]^T, 128x128 tile, BK=32.
// MODE 0: qkv epilogue -- bias; Q scaled by log2(e)/8; Q/K d-index and V^T
//         s-index permuted via swap23 (flash fragment layout).
// MODE 1: proj epilogue (bias, fp32 out)
// ---------------------------------------------------------------------------
template <int MODE>
__global__ __launch_bounds__(256) void gemm_bt(
    const __bf16* __restrict__ A, const __bf16* __restrict__ Bt,
    const float* __restrict__ bias, __bf16* __restrict__ Qb,
    __bf16* __restrict__ Kb, __bf16* __restrict__ VTb,
    float* __restrict__ out, int K, int N) {
  __shared__ __align__(16) __bf16 As[128 * 32];
  __shared__ __align__(16) __bf16 Bs[128 * 32];
  const int tid = threadIdx.x;
  const int wave = tid >> 6, lane = tid & 63;
  const int quad = lane >> 4, c16 = lane & 15;
  const int m0 = blockIdx.y * 128, n0 = blockIdx.x * 128;
  const int wm = (wave >> 1) * 64, wn = (wave & 1) * 64;

  f32x4 acc[4][4] = {};

  for (int k0 = 0; k0 < K; k0 += 32) {
    __syncthreads();
#pragma unroll
    for (int i = 0; i < 2; ++i) {
      const int cb = (i * 4 + wave) * 64;
      const int c = cb + lane;
      const int row = c >> 2, kk = (c & 3) * 8;
      gl2lds16(&A[(size_t)(m0 + row) * K + k0 + kk], &As[cb * 8]);
      gl2lds16(&Bt[(size_t)(n0 + row) * K + k0 + kk], &Bs[cb * 8]);
    }
    __syncthreads();
    bf16x8 af[4], bf[4];
#pragma unroll
    for (int mi = 0; mi < 4; ++mi)
      af[mi] = *(const bf16x8*)&As[(wm + mi * 16 + c16) * 32 + quad * 8];
#pragma unroll
    for (int ni = 0; ni < 4; ++ni)
      bf[ni] = *(const bf16x8*)&Bs[(wn + ni * 16 + c16) * 32 + quad * 8];
#pragma unroll
    for (int mi = 0; mi < 4; ++mi)
#pragma unroll
      for (int ni = 0; ni < 4; ++ni)
        acc[mi][ni] = MFMA16(af[mi], bf[ni], acc[mi][ni]);
  }

#pragma unroll
  for (int mi = 0; mi < 4; ++mi) {
#pragma unroll
    for (int ni = 0; ni < 4; ++ni) {
      const int gcol = n0 + wn + ni * 16 + c16;
      const float bv = bias[gcol];
      const int growb = m0 + wm + mi * 16 + quad * 4;
      if (MODE == 0) {
        const int which = gcol / Ee;
        const int e = gcol - which * Ee;
        const int hh = e >> 6, dd = e & 63;
        const int bb = growb >> 11, ss = growb & 2047;
        const size_t bh = (size_t)(bb * Hh + hh);
        if (which == 2) {  // V^T with permuted s: 4 consecutive ss stay packed
          const int ssp = swap23(ss);
          bf16x4 o;
#pragma unroll
          for (int r = 0; r < 4; ++r) o[r] = (__bf16)(acc[mi][ni][r] + bv);
          *(bf16x4*)&VTb[(bh * Dd + dd) * Ss + ssp] = o;
        } else if (which == 0) {  // Q: permuted d, prescaled
          const int ddp = swap23(dd);
#pragma unroll
          for (int r = 0; r < 4; ++r)
            Qb[(bh * Ss + ss + r) * Dd + ddp] =
                (__bf16)((acc[mi][ni][r] + bv) * QSCALE);
        } else {  // K: permuted d
          const int ddp = swap23(dd);
#pragma unroll
          for (int r = 0; r < 4; ++r)
            Kb[(bh * Ss + ss + r) * Dd + ddp] = (__bf16)(acc[mi][ni][r] + bv);
        }
      } else {
#pragma unroll
        for (int r = 0; r < 4; ++r)
          out[(size_t)(growb + r) * N + gcol] = acc[mi][ni][r] + bv;
      }
    }
  }
}

// ---------------------------------------------------------------------------
// flash attention v6: round-0 structure (32x32x16 MFMA, async 3-buffer K/V
// staging via global_load_lds, XOR-(row&7) swizzle, one raw s_barrier +
// partial vmcnt wait per iteration, prefetch a full iter ahead) plus:
//   - role rotation (w+bidx)&3 so each SIMD hosts mixed strip lengths
//   - tree-shaped max/sum reductions (depth 5, was 31-deep dependent chain)
//   - defer-max (T13): skip O/l rescale when max grows <= 2^11.5
//   - s_setprio(1) around MFMA clusters (T5)
// ---------------------------------------------------------------------------
__global__ __launch_bounds__(256, 3) void flash_attn(
    const __bf16* __restrict__ Qb, const __bf16* __restrict__ Kb,
    const __bf16* __restrict__ VTb, const int* __restrict__ amask,
    __bf16* __restrict__ Yb) {
  const int bid = blockIdx.x;
  const int xcd = bid & 7, j = bid >> 3;
  const int bh = xcd * 6 + (j >> 4);  // 6 (b,h) per XCD for L2 locality
  const int bidx = j & 15;
  const int b = bh / Hh, h = bh - b * Hh;
  const int tid = threadIdx.x, w = tid >> 6, lane = tid & 63;
  const int hl = lane >> 5, l31 = lane & 31;
  const int r7 = l31 & 7;

  // balanced strips {bidx, 31-bidx, 32+bidx, 63-bidx}; rotate role by bidx so
  // a given wave-slot (SIMD) sees a mix of strip lengths across blocks
  const int role = (w + bidx) & 3;
  const int s = ((role & 2) << 4) + ((role & 1) ? 31 - bidx : bidx);
  const int qs = s * 32;
  const int qg = qs + l31;     // this lane's query
  const int ktmax = s >> 1;    // last key-tile this wave participates in
  const int nkt = ((63 - bidx) >> 1) + 1;  // block-uniform iteration count

  const __bf16* Qp = Qb + (size_t)bh * Ss * Dd;
  const __bf16* Kp = Kb + (size_t)bh * Ss * Dd;
  const __bf16* Vp = VTb + (size_t)bh * Dd * Ss;

  __shared__ __align__(16) __bf16 Ksh[3 * 64 * 64];  // 3 x 8KB
  __shared__ __align__(16) __bf16 Vsh[3 * 64 * 64];  // 3 x 8KB
  __shared__ uint64_t ballots[32];

  // Q fragments: contiguous b128 thanks to permuted global layout
  bf16x8 qf[4];
#pragma unroll
  for (int wd = 0; wd < 4; ++wd)
    qf[wd] = *(const bf16x8*)&Qp[(size_t)qg * Dd + wd * 16 + hl * 8];

  // precompute attention-mask ballots for all 32 key-tiles (8 per wave)
#pragma unroll
  for (int i = 0; i < 8; ++i) {
    const int t = w * 8 + i;
    const uint64_t ball = __ballot(amask[b * Ss + t * 64 + lane] != 0);
    if (lane == 0) ballots[t] = ball;
  }
  asm volatile("s_waitcnt lgkmcnt(0)" ::: "memory");  // publish ballots

  // async stage of tile kt into buffer buf (4 gl2lds16 per thread)
  auto stage = [&](int kt, int buf) {
    __bf16* kb = &Ksh[buf * 4096];
    __bf16* vb = &Vsh[buf * 4096];
    const char* ksrc = (const char*)(Kp + (size_t)kt * 64 * Dd);
    const char* vsrc = (const char*)Vp + (size_t)kt * 128;
#pragma unroll
    for (int i = 0; i < 2; ++i) {
      const int cb = i * 256 + w * 64;        // wave-uniform chunk base
      const int p = cb + lane;                // this lane's chunk 0..511
      const int row = p >> 3;
      const int cc = (p & 7) ^ (row & 7);     // XOR swizzle
      gl2lds16(ksrc + (size_t)row * 128 + cc * 16, &kb[cb * 8]);
      gl2lds16(vsrc + (size_t)row * 4096 + cc * 16, &vb[cb * 8]);
    }
  };

  stage(0, 0);
  if (nkt > 1) stage(1, 1);

  f32x16 yacc[2] = {};  // Y^T[d = 32dt + (r&3)+8(r>>2)+4hl][q = l31]
  float m_i = -30000.f, l_i = 0.f;

  for (int kt = 0; kt < nkt; ++kt) {
    // wait for tile kt's staging (keep kt+1's 4 loads in flight), then
    // barrier: publishes buf[kt] and proves everyone left buf[(kt+2)%3]
    if (kt + 1 < nkt)
      asm volatile("s_waitcnt vmcnt(4)\n\ts_barrier" ::: "memory");
    else
      asm volatile("s_waitcnt vmcnt(0)\n\ts_barrier" ::: "memory");
    if (kt + 2 < nkt) stage(kt + 2, (kt + 2) % 3);

    if (kt > ktmax) continue;  // wave above diagonal: staging-only helper
    const int k0 = kt * 64;
    const __bf16* kb = &Ksh[(kt % 3) * 4096];
    const __bf16* vb = &Vsh[(kt % 3) * 4096];

    // S^T = K @ Q^T over two 32-key groups (C rows = keys, cols = queries)
    f32x16 sg[2];
    __builtin_amdgcn_s_setprio(1);
#pragma unroll
    for (int g = 0; g < 2; ++g) {
      f32x16 acc = {};
#pragma unroll
      for (int wd = 0; wd < 4; ++wd) {
        const bf16x8 kf = *(const bf16x8*)&kb[(g * 32 + l31) * 64 +
                                             (((2 * wd + hl) ^ r7) * 8)];
        acc = MFMA32(kf, qf[wd], acc);
      }
      sg[g] = acc;
    }
    __builtin_amdgcn_s_setprio(0);

    // causal mask: only tiles overlapping this wave's diagonal
    if (k0 + 63 > qs) {
#pragma unroll
      for (int g = 0; g < 2; ++g)
#pragma unroll
        for (int r = 0; r < 16; ++r) {
          const int key = k0 + g * 32 + (r & 3) + 8 * (r >> 2) + 4 * hl;
          sg[g][r] = (key <= qg) ? sg[g][r] : -30000.f;
        }
    }
    // attention mask: wave-uniform skip when tile fully valid
    const uint64_t mball = ballots[kt];
    if (mball != ~0ull) {
#pragma unroll
      for (int g = 0; g < 2; ++g)
#pragma unroll
        for (int r = 0; r < 16; ++r) {
          const int kr = g * 32 + (r & 3) + 8 * (r >> 2) + 4 * hl;
          sg[g][r] = ((mball >> kr) & 1) ? sg[g][r] : -30000.f;
        }
    }

    // online softmax in log2 domain; row = lane's q; tree-shaped reductions
    // (depth 5 instead of a 31-deep dependent fmax/add chain)
    float tm[16];
#pragma unroll
    for (int r = 0; r < 16; ++r) tm[r] = fmaxf(sg[0][r], sg[1][r]);
#pragma unroll
    for (int off = 8; off >= 1; off >>= 1)
#pragma unroll
      for (int r = 0; r < 8; ++r)
        if (r < off) tm[r] = fmaxf(tm[r], tm[r + off]);
    const float mx = fmaxf(tm[0], __shfl_xor(tm[0], 32));

    // defer-max (T13): if no q-row's max grew more than 2^11.5 over m_i,
    // keep m_i and skip the O/l rescale entirely
    const bool grow = !__all(mx <= m_i + 11.5f);
    const float mnew = grow ? fmaxf(m_i, mx) : m_i;

    float ts[16];
#pragma unroll
    for (int r = 0; r < 16; ++r) {
      const float e0 = fexp2(sg[0][r] - mnew);
      const float e1 = fexp2(sg[1][r] - mnew);
      sg[0][r] = e0;
      sg[1][r] = e1;
      ts[r] = e0 + e1;
    }
#pragma unroll
    for (int off = 8; off >= 1; off >>= 1)
#pragma unroll
      for (int r = 0; r < 8; ++r)
        if (r < off) ts[r] += ts[r + off];
    const float rs = ts[0] + __shfl_xor(ts[0], 32);

    if (grow) {
      const float alpha = fexp2(m_i - mnew);
      l_i *= alpha;
      m_i = mnew;
#pragma unroll
      for (int dt = 0; dt < 2; ++dt)
#pragma unroll
        for (int r = 0; r < 16; ++r) yacc[dt][r] *= alpha;
    }
    l_i += rs;

    // P^T B-fragments = S^T C-register groups (shared k-slot permutation)
    bf16x8 pf[4];
#pragma unroll
    for (int W = 0; W < 4; ++W) {
      bf16x8 f;
#pragma unroll
      for (int jj = 0; jj < 8; ++jj)
        f[jj] = (__bf16)sg[W >> 1][8 * (W & 1) + jj];
      pf[W] = f;
    }

    // Y^T += V^T @ P^T
    __builtin_amdgcn_s_setprio(1);
#pragma unroll
    for (int dt = 0; dt < 2; ++dt)
#pragma unroll
      for (int W = 0; W < 4; ++W) {
        const bf16x8 vf = *(const bf16x8*)&vb[(dt * 32 + l31) * 64 +
                                             (((2 * W + hl) ^ r7) * 8)];
        yacc[dt] = MFMA32(vf, pf[W], yacc[dt]);
      }
    __builtin_amdgcn_s_setprio(0);
  }

  // normalize; write Y [B,S,E] bf16 (unpermuted -- feeds gemm2)
  const float inv = 1.f / l_i;
  __bf16* yrow = Yb + (size_t)(b * Ss + qg) * Ee + h * Dd;
#pragma unroll
  for (int dt = 0; dt < 2; ++dt)
#pragma unroll
    for (int sreg = 0; sreg < 4; ++sreg) {
      bf16x4 o;
#pragma unroll
      for (int r = 0; r < 4; ++r)
        o[r] = (__bf16)(yacc[dt][sreg * 4 + r] * inv);
      *(bf16x4*)&yrow[dt * 32 + sreg * 8 + hl * 4] = o;
    }
}

// ---------------------------------------------------------------------------
// launch
// ---------------------------------------------------------------------------
extern "C" void kernel_launch(void* const* d_in, const int* in_sizes, int n_in,
                              void* d_out, int out_size, void* d_ws,
                              size_t ws_size, hipStream_t stream) {
  const float* x      = (const float*)d_in[0];
  const float* W_attn = (const float*)d_in[1];
  const float* b_attn = (const float*)d_in[2];
  const float* W_proj = (const float*)d_in[3];
  const float* b_proj = (const float*)d_in[4];
  const int* att_mask = (const int*)d_in[5];
  float* out = (float*)d_out;

  char* ws = (char*)d_ws;
  __bf16* xb  = (__bf16*)(ws);              // 12,582,912  x as bf16 / later Y
  __bf16* Wat = (__bf16*)(ws + 12582912);   //  3,538,944  W_attn^T bf16
  __bf16* Wpt = (__bf16*)(ws + 16121856);   //  1,179,648  W_proj^T bf16
  __bf16* Qb  = (__bf16*)(ws + 17301504);   // Q [B,H,S,D] perm, x log2e/8
  __bf16* Kb  = (__bf16*)(ws + 29884416);   // K [B,H,S,D] perm
  __bf16* VTb = (__bf16*)(ws + 42467328);   // V^T [B,H,D,S] perm
  __bf16* Yb  = xb;

  cast_f32_bf16<<<6144, 256, 0, stream>>>(x, xb, Bb * Ss * Ee);
  transpose_cast<<<dim3(36, 12), 256, 0, stream>>>(W_attn, Wat, Ee, 3 * Ee);
  transpose_cast<<<dim3(12, 12), 256, 0, stream>>>(W_proj, Wpt, Ee, Ee);

  gemm_bt<0><<<dim3(18, 64), 256, 0, stream>>>(xb, Wat, b_attn, Qb, Kb, VTb,
                                               nullptr, Ee, 3 * Ee);
  flash_attn<<<768, 256, 0, stream>>>(Qb, Kb, VTb, att_mask, Yb);
  gemm_bt<1><<<dim3(6, 64), 256, 0, stream>>>(Yb, Wpt, b_proj, nullptr,
                                              nullptr, nullptr, out, Ee, Ee);
}

// Round 3
// 214.423 us; speedup vs baseline: 1.2794x; 1.0774x over previous
//
#include <hip/hip_runtime.h>
#include <cstdint>

// ---------------------------------------------------------------------------
// Causal self-attention block: qkv GEMM (BK=64, swizzled LDS) -> flash
// attention (contiguous 128-query band blocks, 32x32 MFMA, async 3-buffer
// staging) -> proj GEMM. bf16 MFMA, fp32 accumulate.
// B=4 S=2048 E=768 H=12 D=64.
// ---------------------------------------------------------------------------

typedef __bf16 bf16x8 __attribute__((ext_vector_type(8)));
typedef __bf16 bf16x4 __attribute__((ext_vector_type(4)));
typedef float  f32x4  __attribute__((ext_vector_type(4)));
typedef float  f32x16 __attribute__((ext_vector_type(16)));

#define MFMA16(a, b, c) __builtin_amdgcn_mfma_f32_16x16x32_bf16(a, b, c, 0, 0, 0)
#define MFMA32(a, b, c) __builtin_amdgcn_mfma_f32_32x32x16_bf16(a, b, c, 0, 0, 0)

static constexpr int Bb = 4, Ss = 2048, Ee = 768, Hh = 12, Dd = 64;
// softmax scale 1/8 folded with log2(e) so we can use raw v_exp_f32 (2^x)
#define QSCALE 0.18033688011112042f

__device__ __forceinline__ void gl2lds16(const void* g, void* l) {
  __builtin_amdgcn_global_load_lds(
      (const __attribute__((address_space(1))) void*)g,
      (__attribute__((address_space(3))) void*)l, 16, 0, 0);
}

__device__ __forceinline__ float fexp2(float x) {
#if __has_builtin(__builtin_amdgcn_exp2f)
  return __builtin_amdgcn_exp2f(x);
#else
  return exp2f(x);
#endif
}

// swap bits 2<->3: the shared MFMA k-slot permutation baked into K/V layouts
__device__ __forceinline__ int swap23(int x) {
  return (x & ~12) | ((x & 4) << 1) | ((x & 8) >> 1);
}

// ---------------------------------------------------------------------------
// prep kernels
// ---------------------------------------------------------------------------
__global__ void cast_f32_bf16(const float* __restrict__ x,
                              __bf16* __restrict__ y, int n) {
  int i = (blockIdx.x * blockDim.x + threadIdx.x) * 4;
  if (i < n) {
    float4 v = *(const float4*)(x + i);
    bf16x4 o = {(__bf16)v.x, (__bf16)v.y, (__bf16)v.z, (__bf16)v.w};
    *(bf16x4*)(y + i) = o;
  }
}

__global__ void transpose_cast(const float* __restrict__ W,
                               __bf16* __restrict__ Wt, int K, int N) {
  __shared__ float t[64][65];
  const int k0 = blockIdx.y * 64, n0 = blockIdx.x * 64;
#pragma unroll
  for (int i = 0; i < 16; ++i) {
    int lin = i * 256 + threadIdx.x;
    int r = lin >> 6, c = lin & 63;
    t[r][c] = W[(size_t)(k0 + r) * N + n0 + c];
  }
  __syncthreads();
#pragma unroll
  for (int i = 0; i < 16; ++i) {
    int lin = i * 256 + threadIdx.x;
    int r = lin >> 6, c = lin & 63;
    Wt[(size_t)(n0 + r) * K + k0 + c] = (__bf16)t[c][r];
  }
}

// ---------------------------------------------------------------------------
// m97-style GEMM, BK=64: C[M,N] = A[M,K] @ Bt[N,K]^T, 128x128 tile.
// LDS rows are 128B -> XOR-(row&7) 16B-chunk swizzle on BOTH the staging
// source address and the fragment read (conflict-free b128 reads).
// MODE 0: qkv epilogue -- bias; Q^T [bh][d][s] plain layout, prescaled,
//         8B stores; K d-index and V^T s-index permuted via swap23.
// MODE 1: proj epilogue (bias, fp32 out)
// ---------------------------------------------------------------------------
template <int MODE>
__global__ __launch_bounds__(256) void gemm_bt(
    const __bf16* __restrict__ A, const __bf16* __restrict__ Bt,
    const float* __restrict__ bias, __bf16* __restrict__ Qb,
    __bf16* __restrict__ Kb, __bf16* __restrict__ VTb,
    float* __restrict__ out, int K, int N) {
  __shared__ __align__(16) __bf16 As[128 * 64];
  __shared__ __align__(16) __bf16 Bs[128 * 64];
  const int tid = threadIdx.x;
  const int wave = tid >> 6, lane = tid & 63;
  const int quad = lane >> 4, c16 = lane & 15;
  const int m0 = blockIdx.y * 128, n0 = blockIdx.x * 128;
  const int wm = (wave >> 1) * 64, wn = (wave & 1) * 64;

  f32x4 acc[4][4] = {};

  for (int k0 = 0; k0 < K; k0 += 64) {
    __syncthreads();
#pragma unroll
    for (int i = 0; i < 4; ++i) {
      const int cb = (i * 4 + wave) * 64;        // chunk base (wave-uniform)
      const int c = cb + lane;                   // chunk id 0..1023
      const int row = c >> 3;                    // 0..127
      const int kk = ((c & 7) ^ (row & 7)) * 8;  // swizzled source column
      gl2lds16(&A[(size_t)(m0 + row) * K + k0 + kk], &As[cb * 8]);
      gl2lds16(&Bt[(size_t)(n0 + row) * K + k0 + kk], &Bs[cb * 8]);
    }
    __syncthreads();
#pragma unroll
    for (int h = 0; h < 2; ++h) {
      bf16x8 af[4], bf[4];
#pragma unroll
      for (int mi = 0; mi < 4; ++mi) {
        const int R = wm + mi * 16 + c16;
        af[mi] = *(const bf16x8*)&As[R * 64 + (((h * 4 + quad) ^ (R & 7)) * 8)];
      }
#pragma unroll
      for (int ni = 0; ni < 4; ++ni) {
        const int R = wn + ni * 16 + c16;
        bf[ni] = *(const bf16x8*)&Bs[R * 64 + (((h * 4 + quad) ^ (R & 7)) * 8)];
      }
#pragma unroll
      for (int mi = 0; mi < 4; ++mi)
#pragma unroll
        for (int ni = 0; ni < 4; ++ni)
          acc[mi][ni] = MFMA16(af[mi], bf[ni], acc[mi][ni]);
    }
  }

#pragma unroll
  for (int mi = 0; mi < 4; ++mi) {
#pragma unroll
    for (int ni = 0; ni < 4; ++ni) {
      const int gcol = n0 + wn + ni * 16 + c16;
      const float bv = bias[gcol];
      const int growb = m0 + wm + mi * 16 + quad * 4;
      if (MODE == 0) {
        const int which = gcol / Ee;
        const int e = gcol - which * Ee;
        const int hh = e >> 6, dd = e & 63;
        const int bb = growb >> 11, ss = growb & 2047;
        const size_t bh = (size_t)(bb * Hh + hh);
        if (which == 2) {  // V^T with permuted s: 4 consecutive ss stay packed
          const int ssp = swap23(ss);
          bf16x4 o;
#pragma unroll
          for (int r = 0; r < 4; ++r) o[r] = (__bf16)(acc[mi][ni][r] + bv);
          *(bf16x4*)&VTb[(bh * Dd + dd) * Ss + ssp] = o;
        } else if (which == 0) {  // Q^T [bh][d][s] plain, prescaled, 8B store
          bf16x4 o;
#pragma unroll
          for (int r = 0; r < 4; ++r)
            o[r] = (__bf16)((acc[mi][ni][r] + bv) * QSCALE);
          *(bf16x4*)&Qb[(bh * Dd + dd) * Ss + ss] = o;
        } else {  // K: permuted d
          const int ddp = swap23(dd);
#pragma unroll
          for (int r = 0; r < 4; ++r)
            Kb[(bh * Ss + ss + r) * Dd + ddp] = (__bf16)(acc[mi][ni][r] + bv);
        }
      } else {
#pragma unroll
        for (int r = 0; r < 4; ++r)
          out[(size_t)(growb + r) * N + gcol] = acc[mi][ni][r] + bv;
      }
    }
  }
}

// ---------------------------------------------------------------------------
// length-balanced (band, bh_local) assignment for flash blocks.
// Per XCD: 96 blocks = 6 bh x 16 bands; band i costs nkt = 2i+2 iterations.
// j-order interleaves classes L,S,M (period 3). Since 32 % 3 == 2, BOTH
// {3c,3c+1,3c+2} (fill-first) AND {c, c+32, c+64} (round-robin) CU triples
// get one block of each class -> per-CU iteration counts are balanced.
// L: bands 15..11 x6 then 10 x2 (descending); S: 0..4 x6 then 5 x2
// (ascending; L+S = 15 aligned); M: pairs (10,5)x4, (9,6)x6, (8,7)x6.
// ---------------------------------------------------------------------------
__device__ __forceinline__ void band_of(int j, int& band, int& bhl) {
  const int cls = j % 3, q = j / 3;
  if (cls == 0) {
    if (q < 30) { band = 15 - q / 6; bhl = q % 6; }
    else        { band = 10; bhl = q - 30; }
  } else if (cls == 1) {
    if (q < 30) { band = q / 6; bhl = q % 6; }
    else        { band = 5; bhl = q - 30; }
  } else {
    const int p = q >> 1, hi = !(q & 1);
    if (p < 4)       { band = hi ? 10 : 5; bhl = 2 + p; }
    else if (p < 10) { band = hi ? 9 : 6;  bhl = p - 4; }
    else             { band = hi ? 8 : 7;  bhl = p - 10; }
  }
}

// ---------------------------------------------------------------------------
// flash attention v7: block = one contiguous 128-query band (wave w gets
// queries [128*band + 32w, +32)), so ALL waves compute nearly every
// iteration (2 helper-slots per block vs ~40% helper slots before).
// nkt = 2*band+2 varies 2..32; band_of() balances totals across CUs.
// Async 3-buffer K/V staging via global_load_lds with XOR-(row&7) 16B-chunk
// swizzle; one raw s_barrier + partial vmcnt wait per iteration; prefetch a
// full iteration ahead. K/V layouts carry the swap23 k-slot permutation;
// Q^T is plain [bh][d][s] (permutation folded into the one-time gather).
// ---------------------------------------------------------------------------
__global__ __launch_bounds__(256, 3) void flash_attn(
    const __bf16* __restrict__ Qb, const __bf16* __restrict__ Kb,
    const __bf16* __restrict__ VTb, const int* __restrict__ amask,
    __bf16* __restrict__ Yb) {
  const int bid = blockIdx.x;
  const int xcd = bid & 7, j = bid >> 3;
  int band, bhl;
  band_of(j, band, bhl);
  const int bh = xcd * 6 + bhl;  // 6 (b,h) per XCD for L2 locality
  const int b = bh / Hh, h = bh - b * Hh;
  const int tid = threadIdx.x, w = tid >> 6, lane = tid & 63;
  const int hl = lane >> 5, l31 = lane & 31;
  const int r7 = l31 & 7;

  const int qs = band * 128 + w * 32;
  const int qg = qs + l31;              // this lane's query
  const int ktmax = 2 * band + (w >> 1);  // last key-tile for this wave
  const int nkt = 2 * band + 2;           // block-uniform iteration count

  const __bf16* Qp = Qb + (size_t)bh * Dd * Ss;  // Q^T [d][s]
  const __bf16* Kp = Kb + (size_t)bh * Ss * Dd;
  const __bf16* Vp = VTb + (size_t)bh * Dd * Ss;

  __shared__ __align__(16) __bf16 Ksh[3 * 64 * 64];  // 3 x 8KB
  __shared__ __align__(16) __bf16 Vsh[3 * 64 * 64];  // 3 x 8KB
  __shared__ uint64_t ballots[32];

  // Q fragments: one-time strided gather from plain Q^T; the swap23 k-slot
  // permutation is folded into the d index: d = wd*16 + hl*4 + (jj&3) + 2*(jj&4)
  bf16x8 qf[4];
#pragma unroll
  for (int wd = 0; wd < 4; ++wd) {
    bf16x8 f;
#pragma unroll
    for (int jj = 0; jj < 8; ++jj)
      f[jj] = Qp[(size_t)(wd * 16 + hl * 4 + (jj & 3) + ((jj & 4) << 1)) * Ss +
                 qg];
    qf[wd] = f;
  }

  // precompute attention-mask ballots for all 32 key-tiles (8 per wave)
#pragma unroll
  for (int i = 0; i < 8; ++i) {
    const int t = w * 8 + i;
    const uint64_t ball = __ballot(amask[b * Ss + t * 64 + lane] != 0);
    if (lane == 0) ballots[t] = ball;
  }
  asm volatile("s_waitcnt lgkmcnt(0)" ::: "memory");  // publish own writes

  // async stage of tile kt into buffer buf (4 gl2lds16 per thread)
  auto stage = [&](int kt, int buf) {
    __bf16* kb = &Ksh[buf * 4096];
    __bf16* vb = &Vsh[buf * 4096];
    const char* ksrc = (const char*)(Kp + (size_t)kt * 64 * Dd);
    const char* vsrc = (const char*)Vp + (size_t)kt * 128;
#pragma unroll
    for (int i = 0; i < 2; ++i) {
      const int cb = i * 256 + w * 64;        // wave-uniform chunk base
      const int p = cb + lane;                // this lane's chunk 0..511
      const int row = p >> 3;
      const int cc = (p & 7) ^ (row & 7);     // XOR swizzle
      gl2lds16(ksrc + (size_t)row * 128 + cc * 16, &kb[cb * 8]);
      gl2lds16(vsrc + (size_t)row * 4096 + cc * 16, &vb[cb * 8]);
    }
  };

  stage(0, 0);
  stage(1, 1);  // nkt >= 2 always

  f32x16 yacc[2] = {};  // Y^T[d = 32dt + (r&3)+8(r>>2)+4hl][q = l31]
  float m_i = -30000.f, l_i = 0.f;

  for (int kt = 0; kt < nkt; ++kt) {
    // wait for tile kt's staging (keep kt+1's 4 loads in flight), then
    // barrier: publishes buf[kt] and proves everyone left buf[(kt+2)%3]
    if (kt + 1 < nkt)
      asm volatile("s_waitcnt vmcnt(4)\n\ts_barrier" ::: "memory");
    else
      asm volatile("s_waitcnt vmcnt(0)\n\ts_barrier" ::: "memory");
    if (kt + 2 < nkt) stage(kt + 2, (kt + 2) % 3);

    if (kt > ktmax) continue;  // waves 0,1 idle only on the last tile
    const int k0 = kt * 64;
    const __bf16* kb = &Ksh[(kt % 3) * 4096];
    const __bf16* vb = &Vsh[(kt % 3) * 4096];

    // S^T = K @ Q^T over two 32-key groups (C rows = keys, cols = queries)
    f32x16 sg[2];
    __builtin_amdgcn_s_setprio(1);
#pragma unroll
    for (int g = 0; g < 2; ++g) {
      f32x16 acc = {};
#pragma unroll
      for (int wd = 0; wd < 4; ++wd) {
        const bf16x8 kf = *(const bf16x8*)&kb[(g * 32 + l31) * 64 +
                                             (((2 * wd + hl) ^ r7) * 8)];
        acc = MFMA32(kf, qf[wd], acc);
      }
      sg[g] = acc;
    }
    __builtin_amdgcn_s_setprio(0);

    // causal mask: only tiles overlapping this wave's diagonal
    if (k0 + 63 > qs) {
#pragma unroll
      for (int g = 0; g < 2; ++g)
#pragma unroll
        for (int r = 0; r < 16; ++r) {
          const int key = k0 + g * 32 + (r & 3) + 8 * (r >> 2) + 4 * hl;
          sg[g][r] = (key <= qg) ? sg[g][r] : -30000.f;
        }
    }
    // attention mask: wave-uniform skip when tile fully valid
    const uint64_t mball = ballots[kt];
    if (mball != ~0ull) {
#pragma unroll
      for (int g = 0; g < 2; ++g)
#pragma unroll
        for (int r = 0; r < 16; ++r) {
          const int kr = g * 32 + (r & 3) + 8 * (r >> 2) + 4 * hl;
          sg[g][r] = ((mball >> kr) & 1) ? sg[g][r] : -30000.f;
        }
    }

    // online softmax in log2 domain; row = lane's q; tree-shaped reductions
    float tm[16];
#pragma unroll
    for (int r = 0; r < 16; ++r) tm[r] = fmaxf(sg[0][r], sg[1][r]);
#pragma unroll
    for (int off = 8; off >= 1; off >>= 1)
#pragma unroll
      for (int r = 0; r < 8; ++r)
        if (r < off) tm[r] = fmaxf(tm[r], tm[r + off]);
    const float mx = fmaxf(tm[0], __shfl_xor(tm[0], 32));

    // defer-max (T13): skip O/l rescale when max grows <= 2^11.5
    const bool grow = !__all(mx <= m_i + 11.5f);
    const float mnew = grow ? fmaxf(m_i, mx) : m_i;

    float ts[16];
#pragma unroll
    for (int r = 0; r < 16; ++r) {
      const float e0 = fexp2(sg[0][r] - mnew);
      const float e1 = fexp2(sg[1][r] - mnew);
      sg[0][r] = e0;
      sg[1][r] = e1;
      ts[r] = e0 + e1;
    }
#pragma unroll
    for (int off = 8; off >= 1; off >>= 1)
#pragma unroll
      for (int r = 0; r < 8; ++r)
        if (r < off) ts[r] += ts[r + off];
    const float rs = ts[0] + __shfl_xor(ts[0], 32);

    if (grow) {
      const float alpha = fexp2(m_i - mnew);
      l_i *= alpha;
      m_i = mnew;
#pragma unroll
      for (int dt = 0; dt < 2; ++dt)
#pragma unroll
        for (int r = 0; r < 16; ++r) yacc[dt][r] *= alpha;
    }
    l_i += rs;

    // P^T B-fragments = S^T C-register groups (shared k-slot permutation)
    bf16x8 pf[4];
#pragma unroll
    for (int W = 0; W < 4; ++W) {
      bf16x8 f;
#pragma unroll
      for (int jj = 0; jj < 8; ++jj)
        f[jj] = (__bf16)sg[W >> 1][8 * (W & 1) + jj];
      pf[W] = f;
    }

    // Y^T += V^T @ P^T
    __builtin_amdgcn_s_setprio(1);
#pragma unroll
    for (int dt = 0; dt < 2; ++dt)
#pragma unroll
      for (int W = 0; W < 4; ++W) {
        const bf16x8 vf = *(const bf16x8*)&vb[(dt * 32 + l31) * 64 +
                                             (((2 * W + hl) ^ r7) * 8)];
        yacc[dt] = MFMA32(vf, pf[W], yacc[dt]);
      }
    __builtin_amdgcn_s_setprio(0);
  }

  // normalize; write Y [B,S,E] bf16 (unpermuted -- feeds gemm2)
  const float inv = 1.f / l_i;
  __bf16* yrow = Yb + (size_t)(b * Ss + qg) * Ee + h * Dd;
#pragma unroll
  for (int dt = 0; dt < 2; ++dt)
#pragma unroll
    for (int sreg = 0; sreg < 4; ++sreg) {
      bf16x4 o;
#pragma unroll
      for (int r = 0; r < 4; ++r)
        o[r] = (__bf16)(yacc[dt][sreg * 4 + r] * inv);
      *(bf16x4*)&yrow[dt * 32 + sreg * 8 + hl * 4] = o;
    }
}

// ---------------------------------------------------------------------------
// launch
// ---------------------------------------------------------------------------
extern "C" void kernel_launch(void* const* d_in, const int* in_sizes, int n_in,
                              void* d_out, int out_size, void* d_ws,
                              size_t ws_size, hipStream_t stream) {
  const float* x      = (const float*)d_in[0];
  const float* W_attn = (const float*)d_in[1];
  const float* b_attn = (const float*)d_in[2];
  const float* W_proj = (const float*)d_in[3];
  const float* b_proj = (const float*)d_in[4];
  const int* att_mask = (const int*)d_in[5];
  float* out = (float*)d_out;

  char* ws = (char*)d_ws;
  __bf16* xb  = (__bf16*)(ws);              // 12,582,912  x as bf16 / later Y
  __bf16* Wat = (__bf16*)(ws + 12582912);   //  3,538,944  W_attn^T bf16
  __bf16* Wpt = (__bf16*)(ws + 16121856);   //  1,179,648  W_proj^T bf16
  __bf16* Qb  = (__bf16*)(ws + 17301504);   // Q^T [B,H,D,S] plain, x log2e/8
  __bf16* Kb  = (__bf16*)(ws + 29884416);   // K [B,H,S,D] perm
  __bf16* VTb = (__bf16*)(ws + 42467328);   // V^T [B,H,D,S] perm
  __bf16* Yb  = xb;

  cast_f32_bf16<<<6144, 256, 0, stream>>>(x, xb, Bb * Ss * Ee);
  transpose_cast<<<dim3(36, 12), 256, 0, stream>>>(W_attn, Wat, Ee, 3 * Ee);
  transpose_cast<<<dim3(12, 12), 256, 0, stream>>>(W_proj, Wpt, Ee, Ee);

  gemm_bt<0><<<dim3(18, 64), 256, 0, stream>>>(xb, Wat, b_attn, Qb, Kb, VTb,
                                               nullptr, Ee, 3 * Ee);
  flash_attn<<<768, 256, 0, stream>>>(Qb, Kb, VTb, att_mask, Yb);
  gemm_bt<1><<<dim3(6, 64), 256, 0, stream>>>(Yb, Wpt, b_proj, nullptr,
                                              nullptr, nullptr, out, Ee, Ee);
}